// Round 6
// baseline (198.061 us; speedup 1.0000x reference)
//
#include <hip/hip_runtime.h>
#include <math.h>

#define B_ 16
#define T_ 2048
#define D_ 256
#define W_ 128
#define M_ (B_*T_)   // 32768

typedef __attribute__((ext_vector_type(8))) short bf16x8;
typedef __attribute__((ext_vector_type(4))) float f32x4;
typedef unsigned short u16;

static __device__ __forceinline__ u16 f32_bf16_rne(float f) {
    unsigned int u = __float_as_uint(f);
    u += 0x7FFF + ((u >> 16) & 1);
    return (u16)(u >> 16);
}
static __device__ __forceinline__ float bf16_f32(u16 h) {
    return __uint_as_float(((unsigned int)h) << 16);
}
// async global->LDS, 16B per lane.  LDS dest = wave-uniform base + lane*16.
static __device__ __forceinline__ void gload_lds16(const u16* g, u16* l) {
    __builtin_amdgcn_global_load_lds(
        (const __attribute__((address_space(1))) void*)g,
        (__attribute__((address_space(3))) void*)l, 16, 0, 0);
}

// ---------------------------------------------------------------------------
// K0: transpose weights to bf16 [mat][n][k] via LDS tile (coalesced both
// sides).  hi for all 4 mats; lo for Wk only.  Grid (4 mats, 16 tiles 64x64).
// ---------------------------------------------------------------------------
__global__ __launch_bounds__(256) void aft_split_wT(
    const float* __restrict__ Wq, const float* __restrict__ Wk,
    const float* __restrict__ Wv, const float* __restrict__ Wo,
    u16* __restrict__ Wth, u16* __restrict__ Wkl)
{
    __shared__ alignas(16) u16 Th[64][72];
    __shared__ alignas(16) u16 Tl[64][72];
    const float* Ws[4] = {Wq, Wk, Wv, Wo};
    const int mat = blockIdx.x;
    const float* W = Ws[mat];
    const int k0 = (blockIdx.y & 3) * 64;
    const int n0 = (blockIdx.y >> 2) * 64;
    const int tid = threadIdx.x;

    #pragma unroll
    for (int p = 0; p < 4; ++p) {
        const int k = p * 16 + (tid >> 4);
        const int n = (tid & 15) * 4;
        float4 v = *(const float4*)&W[(size_t)(k0 + k) * 256 + n0 + n];
        float vv[4] = {v.x, v.y, v.z, v.w};
        #pragma unroll
        for (int e = 0; e < 4; ++e) {
            u16 h = f32_bf16_rne(vv[e]);
            Th[n + e][k] = h;
            Tl[n + e][k] = f32_bf16_rne(vv[e] - bf16_f32(h));
        }
    }
    __syncthreads();

    const int n  = tid >> 2;
    const int kc = (tid & 3) * 16;
    size_t ob = ((size_t)mat * 256 + n0 + n) * 256 + k0 + kc;
    *(uint4*)&Wth[ob]     = *(const uint4*)&Th[n][kc];
    *(uint4*)&Wth[ob + 8] = *(const uint4*)&Th[n][kc + 8];
    if (mat == 1) {
        size_t ol = ((size_t)(n0 + n)) * 256 + k0 + kc;
        *(uint4*)&Wkl[ol]     = *(const uint4*)&Tl[n][kc];
        *(uint4*)&Wkl[ol + 8] = *(const uint4*)&Tl[n][kc + 8];
    }
}

// ---------------------------------------------------------------------------
// K0b: banded EW precompute. EWb[t][j], j in [0,320): exp(wb[t][s])-1 inside
// band else 0, s = (t & ~63) - 128 + j.  bf16.
// ---------------------------------------------------------------------------
__global__ void aft_ewb(const float* __restrict__ wb, u16* __restrict__ EWb)
{
    const int t = blockIdx.x;
    const int j = threadIdx.x;   // blockDim = 320
    const int s = (t & ~63) - 128 + j;
    const int dlt = s - t;
    float v = 0.f;
    if (s >= 0 && s < T_ && dlt > -W_ && dlt < W_)
        v = expf(wb[(size_t)t * T_ + s]) - 1.0f;
    EWb[(size_t)t * 320 + j] = f32_bf16_rne(v);
}

// ---------------------------------------------------------------------------
// K1: QKV projections.  R2-R5 post-mortem: duration pinned at 47-49us across
// occupancy 17->30%, conflicts 2.5M->0.4M, VALU 27->40% -- the invariant is
// the per-k-step __syncthreads() vmcnt(0) drain (every step serially eats the
// full load latency).  This version: counted-vmcnt 2-phase pipeline (T3+T4).
// Per ITER(k), invariant "[x(k) 2, B(k) 4] outstanding at entry":
//   AWRITE(cur)                      (compiler waits vmcnt<=4; B(k) in flight)
//   XLOAD(k+1) -> regs
//   s_waitcnt vmcnt(2) lgkmcnt(0)    (drains B(k) ONLY; x(k+1) crosses barrier)
//   s_barrier + sched_barrier(0)
//   BSTAGE(k+1 -> other buf)         (post-barrier = race-safe; lands under
//   COMPUTE(cur)                      the 20 MFMAs + 6 ds_reads)
// One barrier/iter is sufficient: any write to buf b happens after a barrier
// preceded by lgkmcnt(0), which drains every wave's ds_reads of b.
// 48KB dbuf LDS -> still 3 blocks/CU.  Numerics byte-identical to R5.
// ---------------------------------------------------------------------------
__global__ __launch_bounds__(256, 3) void aft_qkv_mfma(
    const float* __restrict__ x,
    const u16* __restrict__ Wth, const u16* __restrict__ Wkl,
    u16* __restrict__ ekT, u16* __restrict__ sigqT)
{
    // 2 bufs x 12288 u16: {Ah[64][32] @0, Al @2048, Bs[4][64][32] @4096}
    // epilogue Tr[64][72] = 4608 u16 reuses the front.
    __shared__ alignas(16) u16 sm[24576];   // 48 KiB
    u16* Tr = sm;

    const int tid  = threadIdx.x;
    const int row0 = blockIdx.x * 64;
    const int col0 = blockIdx.y * 64;
    const int b    = row0 >> 11;
    const int t0g  = row0 & (T_ - 1);
    const int lane = tid & 63;
    const int wid  = tid >> 6;           // 0..3
    const int wm   = (wid >> 1) * 32;    // 2 M-groups of 32
    const int wn   = (wid & 1) * 32;     // 2 N-groups of 32
    const int qd   = lane >> 4;
    const int r    = lane & 15;

    f32x4 accq[2][2], acck[2][2], accv[2][2];
    #pragma unroll
    for (int i = 0; i < 2; ++i)
        #pragma unroll
        for (int j = 0; j < 2; ++j) {
            accq[i][j] = (f32x4){0.f, 0.f, 0.f, 0.f};
            acck[i][j] = accq[i][j];
            accv[i][j] = accq[i][j];
        }

    // staging coords: 256 threads cover 64 rows x 32 cols (4 chunks of 8 u16)
    const int crow  = tid >> 2;                 // 0..63
    const int gchk  = tid & 3;                  // this thread's global chunk
    const int cswz  = (crow >> 1) & 3;          // row-dependent chunk XOR
    const int ccols = (gchk ^ cswz) * 8;        // pre-swizzled SOURCE col (B)
    const int aslot = crow * 32 + (gchk ^ cswz) * 8;  // swizzled LDS slot (A)
    const int wbase = wid * 512;                // gload dest: wave chunk (u16)
    // fragment-read slot with the matching XOR (verified R3: conflicts ~0)
    const int sq8   = (qd ^ ((r >> 1) & 3)) * 8;

    const size_t xbase = (size_t)(row0 + crow) * 256 + gchk * 8;   // f32 elems
    const size_t wbrow = (size_t)(col0 + crow) * 256 + ccols;      // u16 elems

    float4 xa, xb;   // x regs for the CURRENT k-step (loaded one ITER ahead)

#define XLOAD(KK) do {                                                       \
    xa = *(const float4*)&x[xbase + (KK)];                                   \
    xb = *(const float4*)&x[xbase + (KK) + 4];                               \
} while (0)

#define BSTAGE(KK, BOFF) do {                                                \
    size_t gb_ = wbrow + (KK);                                               \
    gload_lds16(&Wth[gb_],          &sm[(BOFF) + 4096  + wbase]);            \
    gload_lds16(&Wth[65536 + gb_],  &sm[(BOFF) + 6144  + wbase]);            \
    gload_lds16(&Wkl[gb_],          &sm[(BOFF) + 8192  + wbase]);            \
    gload_lds16(&Wth[131072 + gb_], &sm[(BOFF) + 10240 + wbase]);            \
} while (0)

#define AWRITE(BOFF) do {                                                    \
    float vv_[8] = {xa.x, xa.y, xa.z, xa.w, xb.x, xb.y, xb.z, xb.w};         \
    union { uint4 q; u16 h[8]; } H_, L_;                                     \
    _Pragma("unroll")                                                        \
    for (int e_ = 0; e_ < 8; ++e_) {                                         \
        u16 h_ = f32_bf16_rne(vv_[e_]);                                      \
        H_.h[e_] = h_;                                                       \
        L_.h[e_] = f32_bf16_rne(vv_[e_] - bf16_f32(h_));                     \
    }                                                                        \
    *(uint4*)&sm[(BOFF) + aslot]        = H_.q;                              \
    *(uint4*)&sm[(BOFF) + 2048 + aslot] = L_.q;                              \
} while (0)

#define COMPUTE(BOFF) do {                                                   \
    bf16x8 ah_[2], al_[2];                                                   \
    _Pragma("unroll")                                                        \
    for (int mf = 0; mf < 2; ++mf) {                                         \
        int ar_ = (wm + mf * 16 + r) * 32 + sq8;                             \
        ah_[mf] = *(const bf16x8*)&sm[(BOFF) + ar_];                         \
        al_[mf] = *(const bf16x8*)&sm[(BOFF) + 2048 + ar_];                  \
    }                                                                        \
    _Pragma("unroll")                                                        \
    for (int nf = 0; nf < 2; ++nf) {                                         \
        int br_ = (wn + nf * 16 + r) * 32 + sq8;                             \
        bf16x8 bq_  = *(const bf16x8*)&sm[(BOFF) + 4096  + br_];             \
        bf16x8 bkh_ = *(const bf16x8*)&sm[(BOFF) + 6144  + br_];             \
        bf16x8 bkl_ = *(const bf16x8*)&sm[(BOFF) + 8192  + br_];             \
        bf16x8 bv_  = *(const bf16x8*)&sm[(BOFF) + 10240 + br_];             \
        _Pragma("unroll")                                                    \
        for (int mf = 0; mf < 2; ++mf) {                                     \
            accq[mf][nf] = __builtin_amdgcn_mfma_f32_16x16x32_bf16(ah_[mf], bq_,  accq[mf][nf], 0, 0, 0); \
            acck[mf][nf] = __builtin_amdgcn_mfma_f32_16x16x32_bf16(ah_[mf], bkh_, acck[mf][nf], 0, 0, 0); \
            acck[mf][nf] = __builtin_amdgcn_mfma_f32_16x16x32_bf16(ah_[mf], bkl_, acck[mf][nf], 0, 0, 0); \
            acck[mf][nf] = __builtin_amdgcn_mfma_f32_16x16x32_bf16(al_[mf], bkh_, acck[mf][nf], 0, 0, 0); \
            accv[mf][nf] = __builtin_amdgcn_mfma_f32_16x16x32_bf16(ah_[mf], bv_,  accv[mf][nf], 0, 0, 0); \
        }                                                                    \
    }                                                                        \
} while (0)

    // prologue: establish the invariant [x(0) 2, B(0) 4] outstanding
    XLOAD(0);
    BSTAGE(0, 0);

    #pragma unroll
    for (int ks = 0; ks < 8; ++ks) {
        const int cur = (ks & 1) * 12288;
        const int nxt = 12288 - cur;
        AWRITE(cur);                       // consumes x(ks); B(ks) in flight
        if (ks < 7) {
            XLOAD((ks + 1) * 32);          // x(ks+1) crosses the barrier
            asm volatile("s_waitcnt vmcnt(2) lgkmcnt(0)" ::: "memory");
        } else {
            asm volatile("s_waitcnt vmcnt(0) lgkmcnt(0)" ::: "memory");
        }
        __builtin_amdgcn_s_barrier();
        __builtin_amdgcn_sched_barrier(0); // nothing moves above the barrier
        if (ks < 7) BSTAGE((ks + 1) * 32, nxt);  // lands under COMPUTE
        COMPUTE(cur);
    }
#undef XLOAD
#undef BSTAGE
#undef AWRITE
#undef COMPUTE

    // epilogue: 3 LDS-transpose rounds (ek, ekv, sigq) -> global bf16
    const int dl_r = tid >> 2;            // 0..63
    const int tseg = (tid & 3) * 16;      // 0..48
    #pragma unroll
    for (int round = 0; round < 3; ++round) {
        __syncthreads();
        #pragma unroll
        for (int mf = 0; mf < 2; ++mf) {
            #pragma unroll
            for (int nf = 0; nf < 2; ++nf) {
                ushort4 o;
                float vals[4];
                #pragma unroll
                for (int reg = 0; reg < 4; ++reg) {
                    if (round == 0)      vals[reg] = expf(acck[mf][nf][reg]);
                    else if (round == 1) vals[reg] = expf(acck[mf][nf][reg]) * accv[mf][nf][reg];
                    else                 vals[reg] = 1.f / (1.f + expf(-accq[mf][nf][reg]));
                }
                o.x = f32_bf16_rne(vals[0]); o.y = f32_bf16_rne(vals[1]);
                o.z = f32_bf16_rne(vals[2]); o.w = f32_bf16_rne(vals[3]);
                int dl = wn + nf * 16 + r;
                int tt = wm + mf * 16 + qd * 4;
                *(ushort4*)&Tr[dl * 72 + tt] = o;
            }
        }
        __syncthreads();
        u16* dst;
        if (round == 0)      dst = ekT   + ((size_t)(b * 512 + col0 + dl_r)) * 2048;
        else if (round == 1) dst = ekT   + ((size_t)(b * 512 + 256 + col0 + dl_r)) * 2048;
        else                 dst = sigqT + ((size_t)(b * 256 + col0 + dl_r)) * 2048;
        dst += t0g + tseg;
        const u16* srcp = &Tr[dl_r * 72 + tseg];
        *(uint4*)&dst[0] = *(const uint4*)&srcp[0];
        *(uint4*)&dst[8] = *(const uint4*)&srcp[8];
    }
}

// ---------------------------------------------------------------------------
// K2: row sums of ekT -> Sk (n<256), Sv (n>=256).  One wave per row, plain
// stores (no atomics, no memset needed).
// ---------------------------------------------------------------------------
__global__ __launch_bounds__(256) void aft_sums(
    const u16* __restrict__ ekT, float* __restrict__ Sk, float* __restrict__ Sv)
{
    const int wid  = threadIdx.x >> 6;
    const int lane = threadIdx.x & 63;
    const int row  = blockIdx.x * 4 + wid;   // 0..8191
    const int b = row >> 9, n = row & 511;
    const u16* p = ekT + (size_t)row * 2048 + lane * 32;
    float s = 0.f;
    #pragma unroll
    for (int c = 0; c < 4; ++c) {
        union { uint4 v; u16 h[8]; } u;
        u.v = *(const uint4*)&p[c * 8];
        #pragma unroll
        for (int i = 0; i < 8; ++i) s += bf16_f32(u.h[i]);
    }
    #pragma unroll
    for (int off = 32; off >= 1; off >>= 1) s += __shfl_down(s, off, 64);
    if (lane == 0) {
        if (n < 256) Sk[b * 256 + n] = s;
        else         Sv[b * 256 + n - 256] = s;
    }
}

// ---------------------------------------------------------------------------
// K3: banded num/den via bf16 MFMA.  Block = 64 t x 128 d; wave 64t x 32d
// holds num+den.  Epilogue: y = sig(q)*(Sv+num)/(Sk+den) -> y[b][t][d] bf16.
// ---------------------------------------------------------------------------
__global__ __launch_bounds__(256) void aft_band_mfma(
    const u16* __restrict__ EWb, const u16* __restrict__ ekT,
    const u16* __restrict__ sigqT,
    const float* __restrict__ Sk, const float* __restrict__ Sv,
    u16* __restrict__ yTD)
{
    __shared__ alignas(16) u16 sm[12800];
    u16* Aw  = sm;          // [64][40]
    u16* Bkv = sm + 2560;   // [256][40] : rows 0..127 ek, 128..255 ekv

    const int tid  = threadIdx.x;
    const int t0   = blockIdx.x * 64;
    const int b    = blockIdx.y >> 1;
    const int dh   = (blockIdx.y & 1) * 128;
    const int lane = tid & 63;
    const int wid  = tid >> 6;
    const int wn   = wid * 32;
    const int qd   = lane >> 4;
    const int r    = lane & 15;

    f32x4 accn[4][2], accd[4][2];
    #pragma unroll
    for (int i = 0; i < 4; ++i)
        #pragma unroll
        for (int j = 0; j < 2; ++j) {
            accn[i][j] = (f32x4){0.f, 0.f, 0.f, 0.f};
            accd[i][j] = (f32x4){0.f, 0.f, 0.f, 0.f};
        }

    const int atl = tid >> 2;          // 0..63
    const int ak8 = (tid & 3) * 8;     // 0,8,16,24

    for (int c = 0; c < 10; ++c) {
        const int sc = t0 - 128 + c * 32;
        if (sc < 0 || sc >= T_) continue;   // uniform per block; EW there is 0
        __syncthreads();
        *(uint4*)&Aw[atl * 40 + ak8] =
            *(const uint4*)&EWb[(size_t)(t0 + atl) * 320 + c * 32 + ak8];
        #pragma unroll
        for (int rr = 0; rr < 4; ++rr) {
            int nl = rr * 64 + atl;                        // 0..255
            int n  = (nl < 128) ? (dh + nl) : (256 + dh + nl - 128);
            *(uint4*)&Bkv[nl * 40 + ak8] =
                *(const uint4*)&ekT[((size_t)(b * 512) + n) * 2048 + sc + ak8];
        }
        __syncthreads();

        bf16x8 af[4];
        #pragma unroll
        for (int mf = 0; mf < 4; ++mf)
            af[mf] = *(const bf16x8*)&Aw[(mf * 16 + r) * 40 + qd * 8];
        #pragma unroll
        for (int nf = 0; nf < 2; ++nf) {
            bf16x8 be = *(const bf16x8*)&Bkv[(wn + nf * 16 + r) * 40 + qd * 8];
            bf16x8 bv = *(const bf16x8*)&Bkv[(128 + wn + nf * 16 + r) * 40 + qd * 8];
            #pragma unroll
            for (int mf = 0; mf < 4; ++mf) {
                accd[mf][nf] = __builtin_amdgcn_mfma_f32_16x16x32_bf16(af[mf], be, accd[mf][nf], 0, 0, 0);
                accn[mf][nf] = __builtin_amdgcn_mfma_f32_16x16x32_bf16(af[mf], bv, accn[mf][nf], 0, 0, 0);
            }
        }
    }

    // epilogue: y into LDS [t_local][136] then coalesced store to y[b][t][d]
    __syncthreads();
    u16* Ly = sm;    // [64][136]
    #pragma unroll
    for (int nf = 0; nf < 2; ++nf) {
        const int dl = wn + nf * 16 + r;
        const int d  = dh + dl;
        const float skq = Sk[(b << 8) + d];
        const float svq = Sv[(b << 8) + d];
        #pragma unroll
        for (int mf = 0; mf < 4; ++mf) {
            const int tt = t0 + mf * 16 + qd * 4;
            size_t off = ((size_t)(b << 8) + d) * 2048 + tt;
            ushort4 sg = *(const ushort4*)&sigqT[off];
            float s4[4] = {bf16_f32(sg.x), bf16_f32(sg.y), bf16_f32(sg.z), bf16_f32(sg.w)};
            #pragma unroll
            for (int reg = 0; reg < 4; ++reg) {
                float y = s4[reg] * (svq + accn[mf][nf][reg]) / (skq + accd[mf][nf][reg]);
                Ly[(mf * 16 + qd * 4 + reg) * 136 + dl] = f32_bf16_rne(y);
            }
        }
    }
    __syncthreads();
    {
        const int tl  = tid >> 2;          // 0..63
        const int ds4 = (tid & 3) * 32;    // 0..96
        u16* dst = yTD + ((size_t)b * 2048 + t0 + tl) * 256 + dh + ds4;
        #pragma unroll
        for (int i = 0; i < 4; ++i)
            *(uint4*)&dst[i * 8] = *(const uint4*)&Ly[tl * 136 + ds4 + i * 8];
    }
}

// ---------------------------------------------------------------------------
// K4: out = y @ Wo, single-bf16 both sides.  64 rows x 128 cols per block,
// grid (512, 2).  A staged from y[b][t][d] with vector loads/writes.
// ---------------------------------------------------------------------------
__global__ __launch_bounds__(256) void aft_out_mfma(
    const u16* __restrict__ yTD, const u16* __restrict__ Woth,
    float* __restrict__ out)
{
    __shared__ alignas(16) u16 sm[7680];
    u16* As = sm;           // [64][40]
    u16* Bh = sm + 2560;    // [128][40]

    const int tid  = threadIdx.x;
    const int row0 = blockIdx.x * 64;
    const int col0 = blockIdx.y * 128;
    const int lane = tid & 63;
    const int wid  = tid >> 6;
    const int wn   = wid * 32;
    const int qd   = lane >> 4;
    const int r    = lane & 15;

    f32x4 acc[4][2];
    #pragma unroll
    for (int i = 0; i < 4; ++i)
        #pragma unroll
        for (int j = 0; j < 2; ++j)
            acc[i][j] = (f32x4){0.f, 0.f, 0.f, 0.f};

    const int arow = tid >> 2;          // 0..63
    const int aseg = (tid & 3) * 8;
    const int brw  = tid >> 1;          // 0..127
    const int bsg  = (tid & 1) * 16;

    for (int k0 = 0; k0 < D_; k0 += 32) {
        {
            uint4 v = *(const uint4*)&yTD[(size_t)(row0 + arow) * 256 + k0 + aseg];
            *(uint4*)&As[arow * 40 + aseg] = v;
        }
        {
            size_t g = (size_t)(col0 + brw) * 256 + k0 + bsg;
            uint4 v0 = *(const uint4*)&Woth[g];
            uint4 v1 = *(const uint4*)&Woth[g + 8];
            *(uint4*)&Bh[brw * 40 + bsg]     = v0;
            *(uint4*)&Bh[brw * 40 + bsg + 8] = v1;
        }
        __syncthreads();

        bf16x8 af[4];
        #pragma unroll
        for (int mf = 0; mf < 4; ++mf)
            af[mf] = *(const bf16x8*)&As[(mf * 16 + r) * 40 + qd * 8];
        #pragma unroll
        for (int nf = 0; nf < 2; ++nf) {
            bf16x8 bh = *(const bf16x8*)&Bh[(wn + nf * 16 + r) * 40 + qd * 8];
            #pragma unroll
            for (int mf = 0; mf < 4; ++mf)
                acc[mf][nf] = __builtin_amdgcn_mfma_f32_16x16x32_bf16(af[mf], bh, acc[mf][nf], 0, 0, 0);
        }
        __syncthreads();
    }

    #pragma unroll
    for (int mf = 0; mf < 4; ++mf)
        #pragma unroll
        for (int nf = 0; nf < 2; ++nf)
            #pragma unroll
            for (int reg = 0; reg < 4; ++reg) {
                int mrow = row0 + mf * 16 + qd * 4 + reg;
                int ncol = col0 + wn + nf * 16 + r;
                out[(size_t)mrow * D_ + ncol] = acc[mf][nf][reg];
            }
}

extern "C" void kernel_launch(void* const* d_in, const int* in_sizes, int n_in,
                              void* d_out, int out_size, void* d_ws, size_t ws_size,
                              hipStream_t stream)
{
    const float* x  = (const float*)d_in[0];
    const float* Wq = (const float*)d_in[1];
    const float* Wk = (const float*)d_in[2];
    const float* Wv = (const float*)d_in[3];
    const float* Wo = (const float*)d_in[4];
    const float* wb = (const float*)d_in[5];
    // window (d_in[6]) is the constant 128, baked in as W_.

    u16* Wth   = (u16*)d_ws;                 // 4*65536 = 262144
    u16* Wkl   = Wth + 262144;               // 65536
    u16* EWb   = Wkl + 65536;                // 655360
    u16* ekT   = EWb + 655360;               // 16777216
    u16* sigqT = ekT + 16777216;             // 8388608
    u16* yTD   = sigqT + 8388608;            // 8388608
    float* Sk  = (float*)(yTD + 8388608);    // 4096
    float* Sv  = Sk + 4096;                  // 4096

    aft_split_wT<<<dim3(4, 16), 256, 0, stream>>>(Wq, Wk, Wv, Wo, Wth, Wkl);
    aft_ewb<<<dim3(T_), 320, 0, stream>>>(wb, EWb);
    aft_qkv_mfma<<<dim3(M_ / 64, 4), 256, 0, stream>>>(x, Wth, Wkl, ekT, sigqT);
    aft_sums<<<dim3(8192 / 4), 256, 0, stream>>>(ekT, Sk, Sv);
    aft_band_mfma<<<dim3(T_ / 64, B_ * 2), 256, 0, stream>>>(EWb, ekT, sigqT, Sk, Sv, yTD);
    aft_out_mfma<<<dim3(M_ / 64, 2), 256, 0, stream>>>(yTD, Wth + 3 * 65536, (float*)d_out);
}

// Round 7
// 188.867 us; speedup vs baseline: 1.0487x; 1.0487x over previous
//
#include <hip/hip_runtime.h>
#include <math.h>

#define B_ 16
#define T_ 2048
#define D_ 256
#define W_ 128
#define M_ (B_*T_)   // 32768

typedef __attribute__((ext_vector_type(8))) short bf16x8;
typedef __attribute__((ext_vector_type(4))) float f32x4;
typedef unsigned short u16;

static __device__ __forceinline__ u16 f32_bf16_rne(float f) {
    unsigned int u = __float_as_uint(f);
    u += 0x7FFF + ((u >> 16) & 1);
    return (u16)(u >> 16);
}
static __device__ __forceinline__ float bf16_f32(u16 h) {
    return __uint_as_float(((unsigned int)h) << 16);
}
// async global->LDS, 16B per lane.  LDS dest = wave-uniform base + lane*16.
static __device__ __forceinline__ void gload_lds16(const u16* g, u16* l) {
    __builtin_amdgcn_global_load_lds(
        (const __attribute__((address_space(1))) void*)g,
        (__attribute__((address_space(3))) void*)l, 16, 0, 0);
}

// ---------------------------------------------------------------------------
// K0: transpose weights to bf16 [mat][n][k] via LDS tile (coalesced both
// sides).  hi for all 4 mats; lo for Wk only.  Grid (4 mats, 16 tiles 64x64).
// ---------------------------------------------------------------------------
__global__ __launch_bounds__(256) void aft_split_wT(
    const float* __restrict__ Wq, const float* __restrict__ Wk,
    const float* __restrict__ Wv, const float* __restrict__ Wo,
    u16* __restrict__ Wth, u16* __restrict__ Wkl)
{
    __shared__ alignas(16) u16 Th[64][72];
    __shared__ alignas(16) u16 Tl[64][72];
    const float* Ws[4] = {Wq, Wk, Wv, Wo};
    const int mat = blockIdx.x;
    const float* W = Ws[mat];
    const int k0 = (blockIdx.y & 3) * 64;
    const int n0 = (blockIdx.y >> 2) * 64;
    const int tid = threadIdx.x;

    #pragma unroll
    for (int p = 0; p < 4; ++p) {
        const int k = p * 16 + (tid >> 4);
        const int n = (tid & 15) * 4;
        float4 v = *(const float4*)&W[(size_t)(k0 + k) * 256 + n0 + n];
        float vv[4] = {v.x, v.y, v.z, v.w};
        #pragma unroll
        for (int e = 0; e < 4; ++e) {
            u16 h = f32_bf16_rne(vv[e]);
            Th[n + e][k] = h;
            Tl[n + e][k] = f32_bf16_rne(vv[e] - bf16_f32(h));
        }
    }
    __syncthreads();

    const int n  = tid >> 2;
    const int kc = (tid & 3) * 16;
    size_t ob = ((size_t)mat * 256 + n0 + n) * 256 + k0 + kc;
    *(uint4*)&Wth[ob]     = *(const uint4*)&Th[n][kc];
    *(uint4*)&Wth[ob + 8] = *(const uint4*)&Th[n][kc + 8];
    if (mat == 1) {
        size_t ol = ((size_t)(n0 + n)) * 256 + k0 + kc;
        *(uint4*)&Wkl[ol]     = *(const uint4*)&Tl[n][kc];
        *(uint4*)&Wkl[ol + 8] = *(const uint4*)&Tl[n][kc + 8];
    }
}

// ---------------------------------------------------------------------------
// K0b: banded EW precompute. EWb[t][j], j in [0,320): exp(wb[t][s])-1 inside
// band else 0, s = (t & ~63) - 128 + j.  bf16.
// ---------------------------------------------------------------------------
__global__ void aft_ewb(const float* __restrict__ wb, u16* __restrict__ EWb)
{
    const int t = blockIdx.x;
    const int j = threadIdx.x;   // blockDim = 320
    const int s = (t & ~63) - 128 + j;
    const int dlt = s - t;
    float v = 0.f;
    if (s >= 0 && s < T_ && dlt > -W_ && dlt < W_)
        v = expf(wb[(size_t)t * T_ + s]) - 1.0f;
    EWb[(size_t)t * 320 + j] = f32_bf16_rne(v);
}

// ---------------------------------------------------------------------------
// K1: QKV projections (R5 version, measured best: 47.5us).  R6's counted-vmcnt
// pipeline REGRESSED (50.5us) -- 1-deep prefetch can't cover latency with only
// ~150cy compute/step; reverted.  K1 is at its structural plateau for this
// skinny shape (N=256, K=256): 6 variants all 47-51us.
// Block 64x64, 4 waves (2Mx2N), single-buffered 24KB LDS, 2-barrier loop.
// B staged via global_load_lds (linear dest + pre-swizzled source, rule #21);
// A (x fp32) converted in-register and ds_written to the same swizzled layout.
// Fragment reads use the R3-verified XOR swizzle (conflict-free).
// k = 3-term split: xh*Wkh + xh*Wkl + xl*Wkh (bit-identical).
// ---------------------------------------------------------------------------
__global__ __launch_bounds__(256, 3) void aft_qkv_mfma(
    const float* __restrict__ x,
    const u16* __restrict__ Wth, const u16* __restrict__ Wkl,
    u16* __restrict__ ekT, u16* __restrict__ sigqT)
{
    // main loop: Ah[64][32] + Al[64][32] + Bs[4][64][32] = 12288 u16 (24KB)
    // epilogue:  Tr[64][72] = 4608 u16 reuses the same space
    __shared__ alignas(16) u16 sm[12288];
    u16* Ah = sm;               // [64][32]
    u16* Al = sm + 2048;        // [64][32]
    u16* Bs = sm + 4096;        // [4][64][32]: Wqh, Wkh, Wkl, Wvh
    u16* Tr = sm;               // [64][72] epilogue reuse

    const int tid  = threadIdx.x;
    const int row0 = blockIdx.x * 64;
    const int col0 = blockIdx.y * 64;
    const int b    = row0 >> 11;
    const int t0g  = row0 & (T_ - 1);
    const int lane = tid & 63;
    const int wid  = tid >> 6;           // 0..3
    const int wm   = (wid >> 1) * 32;    // 2 M-groups of 32
    const int wn   = (wid & 1) * 32;     // 2 N-groups of 32
    const int qd   = lane >> 4;
    const int r    = lane & 15;

    f32x4 accq[2][2], acck[2][2], accv[2][2];
    #pragma unroll
    for (int i = 0; i < 2; ++i)
        #pragma unroll
        for (int j = 0; j < 2; ++j) {
            accq[i][j] = (f32x4){0.f, 0.f, 0.f, 0.f};
            acck[i][j] = accq[i][j];
            accv[i][j] = accq[i][j];
        }

    // staging coords: 256 threads cover 64 rows x 32 cols (4 chunks of 8 u16)
    const int crow  = tid >> 2;                 // 0..63
    const int gchk  = tid & 3;                  // this thread's global chunk
    const int cswz  = (crow >> 1) & 3;          // row-dependent chunk XOR
    const int ccols = (gchk ^ cswz) * 8;        // pre-swizzled SOURCE col (B)
    const int aslot = crow * 32 + (gchk ^ cswz) * 8;  // swizzled LDS slot (A)
    const int wbase = wid * 512;                // gload dest: wave chunk (u16)
    // fragment-read slot with the matching XOR (verified R3: conflicts ~0)
    const int sq8   = (qd ^ ((r >> 1) & 3)) * 8;

    for (int k0 = 0; k0 < D_; k0 += 32) {
        if (k0) __syncthreads();          // compute(k-1) reads done
        // stage B: 4 tensors x 64 rows, linear dest + swizzled source
        {
            size_t gb = (size_t)(col0 + crow) * 256 + k0 + ccols;
            gload_lds16(&Wth[gb],          &Bs[0 * 2048 + wbase]);
            gload_lds16(&Wth[65536 + gb],  &Bs[1 * 2048 + wbase]);
            gload_lds16(&Wkl[gb],          &Bs[2 * 2048 + wbase]);
            gload_lds16(&Wth[131072 + gb], &Bs[3 * 2048 + wbase]);
        }
        // stage A: x fp32 -> bf16 hi/lo in-register -> swizzled ds_write
        {
            size_t ga = (size_t)(row0 + crow) * 256 + k0 + gchk * 8;
            float4 v0 = *(const float4*)&x[ga];
            float4 v1 = *(const float4*)&x[ga + 4];
            float vv[8] = {v0.x, v0.y, v0.z, v0.w, v1.x, v1.y, v1.z, v1.w};
            union { uint4 q; u16 h[8]; } H, L;
            #pragma unroll
            for (int e = 0; e < 8; ++e) {
                u16 h = f32_bf16_rne(vv[e]);
                H.h[e] = h;
                L.h[e] = f32_bf16_rne(vv[e] - bf16_f32(h));
            }
            *(uint4*)&Ah[aslot] = H.q;
            *(uint4*)&Al[aslot] = L.q;
        }
        __syncthreads();                  // drains vmcnt (B) + lgkm (A writes)

        bf16x8 ah[2], al[2];
        #pragma unroll
        for (int mf = 0; mf < 2; ++mf) {
            int ar = (wm + mf * 16 + r) * 32 + sq8;
            ah[mf] = *(const bf16x8*)&Ah[ar];
            al[mf] = *(const bf16x8*)&Al[ar];
        }
        #pragma unroll
        for (int nf = 0; nf < 2; ++nf) {
            int br = (wn + nf * 16 + r) * 32 + sq8;
            bf16x8 bq  = *(const bf16x8*)&Bs[br];
            bf16x8 bkh = *(const bf16x8*)&Bs[2048 + br];
            bf16x8 bkl = *(const bf16x8*)&Bs[4096 + br];
            bf16x8 bv  = *(const bf16x8*)&Bs[6144 + br];
            #pragma unroll
            for (int mf = 0; mf < 2; ++mf) {
                accq[mf][nf] = __builtin_amdgcn_mfma_f32_16x16x32_bf16(ah[mf], bq,  accq[mf][nf], 0, 0, 0);
                acck[mf][nf] = __builtin_amdgcn_mfma_f32_16x16x32_bf16(ah[mf], bkh, acck[mf][nf], 0, 0, 0);
                acck[mf][nf] = __builtin_amdgcn_mfma_f32_16x16x32_bf16(ah[mf], bkl, acck[mf][nf], 0, 0, 0);
                acck[mf][nf] = __builtin_amdgcn_mfma_f32_16x16x32_bf16(al[mf], bkh, acck[mf][nf], 0, 0, 0);
                accv[mf][nf] = __builtin_amdgcn_mfma_f32_16x16x32_bf16(ah[mf], bv,  accv[mf][nf], 0, 0, 0);
            }
        }
    }

    // epilogue: 3 LDS-transpose rounds (ek, ekv, sigq) -> global bf16
    const int dl_r = tid >> 2;            // 0..63
    const int tseg = (tid & 3) * 16;      // 0..48
    #pragma unroll
    for (int round = 0; round < 3; ++round) {
        __syncthreads();
        #pragma unroll
        for (int mf = 0; mf < 2; ++mf) {
            #pragma unroll
            for (int nf = 0; nf < 2; ++nf) {
                ushort4 o;
                float vals[4];
                #pragma unroll
                for (int reg = 0; reg < 4; ++reg) {
                    if (round == 0)      vals[reg] = expf(acck[mf][nf][reg]);
                    else if (round == 1) vals[reg] = expf(acck[mf][nf][reg]) * accv[mf][nf][reg];
                    else                 vals[reg] = 1.f / (1.f + expf(-accq[mf][nf][reg]));
                }
                o.x = f32_bf16_rne(vals[0]); o.y = f32_bf16_rne(vals[1]);
                o.z = f32_bf16_rne(vals[2]); o.w = f32_bf16_rne(vals[3]);
                int dl = wn + nf * 16 + r;
                int tt = wm + mf * 16 + qd * 4;
                *(ushort4*)&Tr[dl * 72 + tt] = o;
            }
        }
        __syncthreads();
        u16* dst;
        if (round == 0)      dst = ekT   + ((size_t)(b * 512 + col0 + dl_r)) * 2048;
        else if (round == 1) dst = ekT   + ((size_t)(b * 512 + 256 + col0 + dl_r)) * 2048;
        else                 dst = sigqT + ((size_t)(b * 256 + col0 + dl_r)) * 2048;
        dst += t0g + tseg;
        const u16* srcp = &Tr[dl_r * 72 + tseg];
        *(uint4*)&dst[0] = *(const uint4*)&srcp[0];
        *(uint4*)&dst[8] = *(const uint4*)&srcp[8];
    }
}

// ---------------------------------------------------------------------------
// K2: row sums of ekT -> Sk (n<256), Sv (n>=256).  One wave per row, plain
// stores (no atomics, no memset needed).
// ---------------------------------------------------------------------------
__global__ __launch_bounds__(256) void aft_sums(
    const u16* __restrict__ ekT, float* __restrict__ Sk, float* __restrict__ Sv)
{
    const int wid  = threadIdx.x >> 6;
    const int lane = threadIdx.x & 63;
    const int row  = blockIdx.x * 4 + wid;   // 0..8191
    const int b = row >> 9, n = row & 511;
    const u16* p = ekT + (size_t)row * 2048 + lane * 32;
    float s = 0.f;
    #pragma unroll
    for (int c = 0; c < 4; ++c) {
        union { uint4 v; u16 h[8]; } u;
        u.v = *(const uint4*)&p[c * 8];
        #pragma unroll
        for (int i = 0; i < 8; ++i) s += bf16_f32(u.h[i]);
    }
    #pragma unroll
    for (int off = 32; off >= 1; off >>= 1) s += __shfl_down(s, off, 64);
    if (lane == 0) {
        if (n < 256) Sk[b * 256 + n] = s;
        else         Sv[b * 256 + n - 256] = s;
    }
}

// ---------------------------------------------------------------------------
// K3: banded num/den via bf16 MFMA.  Block = 64 t x 128 d; wave 64t x 32d
// holds num+den.  R6->R7: staging ported to the R5-verified pattern --
// global_load_lds (zero staging VALU), linear stride-32 LDS, pre-swizzled
// SOURCE columns + matching XOR on fragment reads (rule #21 both-sides).
// Epilogue: y = sig(q)*(Sv+num)/(Sk+den) -> y[b][t][d] bf16.
// ---------------------------------------------------------------------------
__global__ __launch_bounds__(256) void aft_band_mfma(
    const u16* __restrict__ EWb, const u16* __restrict__ ekT,
    const u16* __restrict__ sigqT,
    const float* __restrict__ Sk, const float* __restrict__ Sv,
    u16* __restrict__ yTD)
{
    // main loop: Aw[64][32] @0 (2048 u16) + Bkv[256][32] @2048 (8192 u16)
    // epilogue:  Ly[64][136] = 8704 u16 reuses the front
    __shared__ alignas(16) u16 sm[10240];
    u16* Aw  = sm;          // [64][32]
    u16* Bkv = sm + 2048;   // [256][32] : rows 0..127 ek, 128..255 ekv

    const int tid  = threadIdx.x;
    const int t0   = blockIdx.x * 64;
    const int b    = blockIdx.y >> 1;
    const int dh   = (blockIdx.y & 1) * 128;
    const int lane = tid & 63;
    const int wid  = tid >> 6;
    const int wn   = wid * 32;
    const int qd   = lane >> 4;
    const int r    = lane & 15;

    f32x4 accn[4][2], accd[4][2];
    #pragma unroll
    for (int i = 0; i < 4; ++i)
        #pragma unroll
        for (int j = 0; j < 2; ++j) {
            accn[i][j] = (f32x4){0.f, 0.f, 0.f, 0.f};
            accd[i][j] = (f32x4){0.f, 0.f, 0.f, 0.f};
        }

    // staging coords (R5 pattern): 256 threads cover 64 rows x 32 cols
    const int crow  = tid >> 2;                 // 0..63
    const int gchk  = tid & 3;
    const int cswz  = (crow >> 1) & 3;
    const int ccols = (gchk ^ cswz) * 8;        // pre-swizzled SOURCE col
    const int wbase = wid * 512;                // gload dest: wave chunk (u16)
    const int sq8   = (qd ^ ((r >> 1) & 3)) * 8;

    for (int c = 0; c < 10; ++c) {
        const int sc = t0 - 128 + c * 32;
        if (sc < 0 || sc >= T_) continue;   // uniform per block; EW there is 0
        __syncthreads();                    // prior compute's ds_reads done
        // stage A: EWb 64 rows x 32 cols
        gload_lds16(&EWb[(size_t)(t0 + crow) * 320 + c * 32 + ccols],
                    &Aw[wbase]);
        // stage B: ek/ekv 256 rows x 32 cols (4 issues of 64 rows)
        #pragma unroll
        for (int rr = 0; rr < 4; ++rr) {
            int nl = rr * 64 + crow;                       // 0..255
            int n  = (nl < 128) ? (dh + nl) : (256 + dh + nl - 128);
            gload_lds16(&ekT[((size_t)(b * 512) + n) * 2048 + sc + ccols],
                        &Bkv[rr * 2048 + wbase]);
        }
        __syncthreads();                    // vmcnt(0): staged data landed

        bf16x8 af[4];
        #pragma unroll
        for (int mf = 0; mf < 4; ++mf)
            af[mf] = *(const bf16x8*)&Aw[(mf * 16 + r) * 32 + sq8];
        #pragma unroll
        for (int nf = 0; nf < 2; ++nf) {
            bf16x8 be = *(const bf16x8*)&Bkv[(wn + nf * 16 + r) * 32 + sq8];
            bf16x8 bv = *(const bf16x8*)&Bkv[(128 + wn + nf * 16 + r) * 32 + sq8];
            #pragma unroll
            for (int mf = 0; mf < 4; ++mf) {
                accd[mf][nf] = __builtin_amdgcn_mfma_f32_16x16x32_bf16(af[mf], be, accd[mf][nf], 0, 0, 0);
                accn[mf][nf] = __builtin_amdgcn_mfma_f32_16x16x32_bf16(af[mf], bv, accn[mf][nf], 0, 0, 0);
            }
        }
    }

    // epilogue: y into LDS [t_local][136] then coalesced store to y[b][t][d]
    __syncthreads();
    u16* Ly = sm;    // [64][136]
    #pragma unroll
    for (int nf = 0; nf < 2; ++nf) {
        const int dl = wn + nf * 16 + r;
        const int d  = dh + dl;
        const float skq = Sk[(b << 8) + d];
        const float svq = Sv[(b << 8) + d];
        #pragma unroll
        for (int mf = 0; mf < 4; ++mf) {
            const int tt = t0 + mf * 16 + qd * 4;
            size_t off = ((size_t)(b << 8) + d) * 2048 + tt;
            ushort4 sg = *(const ushort4*)&sigqT[off];
            float s4[4] = {bf16_f32(sg.x), bf16_f32(sg.y), bf16_f32(sg.z), bf16_f32(sg.w)};
            #pragma unroll
            for (int reg = 0; reg < 4; ++reg) {
                float y = s4[reg] * (svq + accn[mf][nf][reg]) / (skq + accd[mf][nf][reg]);
                Ly[(mf * 16 + qd * 4 + reg) * 136 + dl] = f32_bf16_rne(y);
            }
        }
    }
    __syncthreads();
    {
        const int tl  = tid >> 2;          // 0..63
        const int ds4 = (tid & 3) * 32;    // 0..96
        u16* dst = yTD + ((size_t)b * 2048 + t0 + tl) * 256 + dh + ds4;
        #pragma unroll
        for (int i = 0; i < 4; ++i)
            *(uint4*)&dst[i * 8] = *(const uint4*)&Ly[tl * 136 + ds4 + i * 8];
    }
}

// ---------------------------------------------------------------------------
// K4: out = y @ Wo, single-bf16 both sides.  64 rows x 128 cols per block,
// grid (512, 2).  R6->R7: staging ported to the R5-verified global_load_lds
// pattern (both A=yTD and B=Woth are bf16 in global): zero staging VALU,
// linear stride-32 LDS + both-sides XOR swizzle.
// ---------------------------------------------------------------------------
__global__ __launch_bounds__(256) void aft_out_mfma(
    const u16* __restrict__ yTD, const u16* __restrict__ Woth,
    float* __restrict__ out)
{
    __shared__ alignas(16) u16 sm[6144];
    u16* As = sm;           // [64][32]
    u16* Bh = sm + 2048;    // [128][32]

    const int tid  = threadIdx.x;
    const int row0 = blockIdx.x * 64;
    const int col0 = blockIdx.y * 128;
    const int lane = tid & 63;
    const int wid  = tid >> 6;
    const int wn   = wid * 32;
    const int qd   = lane >> 4;
    const int r    = lane & 15;

    f32x4 acc[4][2];
    #pragma unroll
    for (int i = 0; i < 4; ++i)
        #pragma unroll
        for (int j = 0; j < 2; ++j)
            acc[i][j] = (f32x4){0.f, 0.f, 0.f, 0.f};

    const int crow  = tid >> 2;                 // 0..63
    const int gchk  = tid & 3;
    const int cswz  = (crow >> 1) & 3;
    const int ccols = (gchk ^ cswz) * 8;        // pre-swizzled SOURCE col
    const int wbase = wid * 512;
    const int sq8   = (qd ^ ((r >> 1) & 3)) * 8;

    for (int k0 = 0; k0 < D_; k0 += 32) {
        if (k0) __syncthreads();
        // stage A: yTD 64 rows; stage B: Woth 128 rows (2 issues)
        gload_lds16(&yTD[(size_t)(row0 + crow) * 256 + k0 + ccols],
                    &As[wbase]);
        gload_lds16(&Woth[(size_t)(col0 + crow) * 256 + k0 + ccols],
                    &Bh[wbase]);
        gload_lds16(&Woth[(size_t)(col0 + 64 + crow) * 256 + k0 + ccols],
                    &Bh[2048 + wbase]);
        __syncthreads();

        bf16x8 af[4];
        #pragma unroll
        for (int mf = 0; mf < 4; ++mf)
            af[mf] = *(const bf16x8*)&As[(mf * 16 + r) * 32 + sq8];
        #pragma unroll
        for (int nf = 0; nf < 2; ++nf) {
            bf16x8 bh = *(const bf16x8*)&Bh[(wn + nf * 16 + r) * 32 + sq8];
            #pragma unroll
            for (int mf = 0; mf < 4; ++mf)
                acc[mf][nf] = __builtin_amdgcn_mfma_f32_16x16x32_bf16(af[mf], bh, acc[mf][nf], 0, 0, 0);
        }
    }

    #pragma unroll
    for (int mf = 0; mf < 4; ++mf)
        #pragma unroll
        for (int nf = 0; nf < 2; ++nf)
            #pragma unroll
            for (int reg = 0; reg < 4; ++reg) {
                int mrow = row0 + mf * 16 + qd * 4 + reg;
                int ncol = col0 + wn + nf * 16 + r;
                out[(size_t)mrow * D_ + ncol] = acc[mf][nf][reg];
            }
}

extern "C" void kernel_launch(void* const* d_in, const int* in_sizes, int n_in,
                              void* d_out, int out_size, void* d_ws, size_t ws_size,
                              hipStream_t stream)
{
    const float* x  = (const float*)d_in[0];
    const float* Wq = (const float*)d_in[1];
    const float* Wk = (const float*)d_in[2];
    const float* Wv = (const float*)d_in[3];
    const float* Wo = (const float*)d_in[4];
    const float* wb = (const float*)d_in[5];
    // window (d_in[6]) is the constant 128, baked in as W_.

    u16* Wth   = (u16*)d_ws;                 // 4*65536 = 262144
    u16* Wkl   = Wth + 262144;               // 65536
    u16* EWb   = Wkl + 65536;                // 655360
    u16* ekT   = EWb + 655360;               // 16777216
    u16* sigqT = ekT + 16777216;             // 8388608
    u16* yTD   = sigqT + 8388608;            // 8388608
    float* Sk  = (float*)(yTD + 8388608);    // 4096
    float* Sv  = Sk + 4096;                  // 4096

    aft_split_wT<<<dim3(4, 16), 256, 0, stream>>>(Wq, Wk, Wv, Wo, Wth, Wkl);
    aft_ewb<<<dim3(T_), 320, 0, stream>>>(wb, EWb);
    aft_qkv_mfma<<<dim3(M_ / 64, 4), 256, 0, stream>>>(x, Wth, Wkl, ekT, sigqT);
    aft_sums<<<dim3(8192 / 4), 256, 0, stream>>>(ekT, Sk, Sv);
    aft_band_mfma<<<dim3(T_ / 64, B_ * 2), 256, 0, stream>>>(EWb, ekT, sigqT, Sk, Sv, yTD);
    aft_out_mfma<<<dim3(M_ / 64, 2), 256, 0, stream>>>(yTD, Wth + 3 * 65536, (float*)d_out);
}

// Round 9
// 176.421 us; speedup vs baseline: 1.1227x; 1.0705x over previous
//
#include <hip/hip_runtime.h>
#include <math.h>

#define B_ 16
#define T_ 2048
#define D_ 256
#define W_ 128
#define M_ (B_*T_)   // 32768

typedef __attribute__((ext_vector_type(8))) short bf16x8;
typedef __attribute__((ext_vector_type(4))) float f32x4;
typedef unsigned short u16;

static __device__ __forceinline__ u16 f32_bf16_rne(float f) {
    unsigned int u = __float_as_uint(f);
    u += 0x7FFF + ((u >> 16) & 1);
    return (u16)(u >> 16);
}
static __device__ __forceinline__ float bf16_f32(u16 h) {
    return __uint_as_float(((unsigned int)h) << 16);
}
// async global->LDS, 16B per lane.  LDS dest = wave-uniform base + lane*16.
static __device__ __forceinline__ void gload_lds16(const u16* g, u16* l) {
    __builtin_amdgcn_global_load_lds(
        (const __attribute__((address_space(1))) void*)g,
        (__attribute__((address_space(3))) void*)l, 16, 0, 0);
}

// ---------------------------------------------------------------------------
// K0: transpose weights to bf16 [mat][n][k] via LDS tile (coalesced both
// sides).  hi for all 4 mats; lo for Wk only.  Grid (4 mats, 16 tiles 64x64).
// ---------------------------------------------------------------------------
__global__ __launch_bounds__(256) void aft_split_wT(
    const float* __restrict__ Wq, const float* __restrict__ Wk,
    const float* __restrict__ Wv, const float* __restrict__ Wo,
    u16* __restrict__ Wth, u16* __restrict__ Wkl)
{
    __shared__ alignas(16) u16 Th[64][72];
    __shared__ alignas(16) u16 Tl[64][72];
    const float* Ws[4] = {Wq, Wk, Wv, Wo};
    const int mat = blockIdx.x;
    const float* W = Ws[mat];
    const int k0 = (blockIdx.y & 3) * 64;
    const int n0 = (blockIdx.y >> 2) * 64;
    const int tid = threadIdx.x;

    #pragma unroll
    for (int p = 0; p < 4; ++p) {
        const int k = p * 16 + (tid >> 4);
        const int n = (tid & 15) * 4;
        float4 v = *(const float4*)&W[(size_t)(k0 + k) * 256 + n0 + n];
        float vv[4] = {v.x, v.y, v.z, v.w};
        #pragma unroll
        for (int e = 0; e < 4; ++e) {
            u16 h = f32_bf16_rne(vv[e]);
            Th[n + e][k] = h;
            Tl[n + e][k] = f32_bf16_rne(vv[e] - bf16_f32(h));
        }
    }
    __syncthreads();

    const int n  = tid >> 2;
    const int kc = (tid & 3) * 16;
    size_t ob = ((size_t)mat * 256 + n0 + n) * 256 + k0 + kc;
    *(uint4*)&Wth[ob]     = *(const uint4*)&Th[n][kc];
    *(uint4*)&Wth[ob + 8] = *(const uint4*)&Th[n][kc + 8];
    if (mat == 1) {
        size_t ol = ((size_t)(n0 + n)) * 256 + k0 + kc;
        *(uint4*)&Wkl[ol]     = *(const uint4*)&Tl[n][kc];
        *(uint4*)&Wkl[ol + 8] = *(const uint4*)&Tl[n][kc + 8];
    }
}

// ---------------------------------------------------------------------------
// K0b: banded EW precompute. EWb[t][j], j in [0,320): exp(wb[t][s])-1 inside
// band else 0, s = (t & ~63) - 128 + j.  bf16.
// ---------------------------------------------------------------------------
__global__ void aft_ewb(const float* __restrict__ wb, u16* __restrict__ EWb)
{
    const int t = blockIdx.x;
    const int j = threadIdx.x;   // blockDim = 320
    const int s = (t & ~63) - 128 + j;
    const int dlt = s - t;
    float v = 0.f;
    if (s >= 0 && s < T_ && dlt > -W_ && dlt < W_)
        v = expf(wb[(size_t)t * T_ + s]) - 1.0f;
    EWb[(size_t)t * 320 + j] = f32_bf16_rne(v);
}

// ---------------------------------------------------------------------------
// K1: QKV projections (R5/R7 main loop, measured plateau 46.5us).  Epilogue
// also emits per-(row, t-block) partial sums of ek/ekv into Skp (f32), so K2
// no longer re-reads the 33.5MB ekT.
// ---------------------------------------------------------------------------
__global__ __launch_bounds__(256, 3) void aft_qkv_mfma(
    const float* __restrict__ x,
    const u16* __restrict__ Wth, const u16* __restrict__ Wkl,
    u16* __restrict__ ekT, u16* __restrict__ sigqT, float* __restrict__ Skp)
{
    // main loop: Ah[64][32] + Al[64][32] + Bs[4][64][32] = 12288 u16 (24KB)
    // epilogue:  Tr[64][72] = 4608 u16 reuses the same space
    __shared__ alignas(16) u16 sm[12288];
    u16* Ah = sm;               // [64][32]
    u16* Al = sm + 2048;        // [64][32]
    u16* Bs = sm + 4096;        // [4][64][32]: Wqh, Wkh, Wkl, Wvh
    u16* Tr = sm;               // [64][72] epilogue reuse

    const int tid  = threadIdx.x;
    const int row0 = blockIdx.x * 64;
    const int col0 = blockIdx.y * 64;
    const int b    = row0 >> 11;
    const int t0g  = row0 & (T_ - 1);
    const int tblk = blockIdx.x & 31;    // t-block index within batch b
    const int lane = tid & 63;
    const int wid  = tid >> 6;           // 0..3
    const int wm   = (wid >> 1) * 32;    // 2 M-groups of 32
    const int wn   = (wid & 1) * 32;     // 2 N-groups of 32
    const int qd   = lane >> 4;
    const int r    = lane & 15;

    f32x4 accq[2][2], acck[2][2], accv[2][2];
    #pragma unroll
    for (int i = 0; i < 2; ++i)
        #pragma unroll
        for (int j = 0; j < 2; ++j) {
            accq[i][j] = (f32x4){0.f, 0.f, 0.f, 0.f};
            acck[i][j] = accq[i][j];
            accv[i][j] = accq[i][j];
        }

    // staging coords: 256 threads cover 64 rows x 32 cols (4 chunks of 8 u16)
    const int crow  = tid >> 2;                 // 0..63
    const int gchk  = tid & 3;                  // this thread's global chunk
    const int cswz  = (crow >> 1) & 3;          // row-dependent chunk XOR
    const int ccols = (gchk ^ cswz) * 8;        // pre-swizzled SOURCE col (B)
    const int aslot = crow * 32 + (gchk ^ cswz) * 8;  // swizzled LDS slot (A)
    const int wbase = wid * 512;                // gload dest: wave chunk (u16)
    // fragment-read slot with the matching XOR (verified R3: conflicts ~0)
    const int sq8   = (qd ^ ((r >> 1) & 3)) * 8;

    for (int k0 = 0; k0 < D_; k0 += 32) {
        if (k0) __syncthreads();          // compute(k-1) reads done
        // stage B: 4 tensors x 64 rows, linear dest + swizzled source
        {
            size_t gb = (size_t)(col0 + crow) * 256 + k0 + ccols;
            gload_lds16(&Wth[gb],          &Bs[0 * 2048 + wbase]);
            gload_lds16(&Wth[65536 + gb],  &Bs[1 * 2048 + wbase]);
            gload_lds16(&Wkl[gb],          &Bs[2 * 2048 + wbase]);
            gload_lds16(&Wth[131072 + gb], &Bs[3 * 2048 + wbase]);
        }
        // stage A: x fp32 -> bf16 hi/lo in-register -> swizzled ds_write
        // (source col UNswizzled gchk*8, dest slot swizzled -- rule #21)
        {
            size_t ga = (size_t)(row0 + crow) * 256 + k0 + gchk * 8;
            float4 v0 = *(const float4*)&x[ga];
            float4 v1 = *(const float4*)&x[ga + 4];
            float vv[8] = {v0.x, v0.y, v0.z, v0.w, v1.x, v1.y, v1.z, v1.w};
            union { uint4 q; u16 h[8]; } H, L;
            #pragma unroll
            for (int e = 0; e < 8; ++e) {
                u16 h = f32_bf16_rne(vv[e]);
                H.h[e] = h;
                L.h[e] = f32_bf16_rne(vv[e] - bf16_f32(h));
            }
            *(uint4*)&Ah[aslot] = H.q;
            *(uint4*)&Al[aslot] = L.q;
        }
        __syncthreads();                  // drains vmcnt (B) + lgkm (A writes)

        bf16x8 ah[2], al[2];
        #pragma unroll
        for (int mf = 0; mf < 2; ++mf) {
            int ar = (wm + mf * 16 + r) * 32 + sq8;
            ah[mf] = *(const bf16x8*)&Ah[ar];
            al[mf] = *(const bf16x8*)&Al[ar];
        }
        #pragma unroll
        for (int nf = 0; nf < 2; ++nf) {
            int br = (wn + nf * 16 + r) * 32 + sq8;
            bf16x8 bq  = *(const bf16x8*)&Bs[br];
            bf16x8 bkh = *(const bf16x8*)&Bs[2048 + br];
            bf16x8 bkl = *(const bf16x8*)&Bs[4096 + br];
            bf16x8 bv  = *(const bf16x8*)&Bs[6144 + br];
            #pragma unroll
            for (int mf = 0; mf < 2; ++mf) {
                accq[mf][nf] = __builtin_amdgcn_mfma_f32_16x16x32_bf16(ah[mf], bq,  accq[mf][nf], 0, 0, 0);
                acck[mf][nf] = __builtin_amdgcn_mfma_f32_16x16x32_bf16(ah[mf], bkh, acck[mf][nf], 0, 0, 0);
                acck[mf][nf] = __builtin_amdgcn_mfma_f32_16x16x32_bf16(ah[mf], bkl, acck[mf][nf], 0, 0, 0);
                acck[mf][nf] = __builtin_amdgcn_mfma_f32_16x16x32_bf16(al[mf], bkh, acck[mf][nf], 0, 0, 0);
                accv[mf][nf] = __builtin_amdgcn_mfma_f32_16x16x32_bf16(ah[mf], bv,  accv[mf][nf], 0, 0, 0);
            }
        }
    }

    // epilogue: 3 LDS-transpose rounds (ek, ekv, sigq) -> global bf16.
    // rounds 0/1 also emit f32 partial row-sums (over this block's 64 t).
    const int dl_r = tid >> 2;            // 0..63
    const int tseg = (tid & 3) * 16;      // 0..48
    #pragma unroll
    for (int round = 0; round < 3; ++round) {
        __syncthreads();
        #pragma unroll
        for (int mf = 0; mf < 2; ++mf) {
            #pragma unroll
            for (int nf = 0; nf < 2; ++nf) {
                ushort4 o;
                float vals[4];
                #pragma unroll
                for (int reg = 0; reg < 4; ++reg) {
                    if (round == 0)      vals[reg] = expf(acck[mf][nf][reg]);
                    else if (round == 1) vals[reg] = expf(acck[mf][nf][reg]) * accv[mf][nf][reg];
                    else                 vals[reg] = 1.f / (1.f + expf(-accq[mf][nf][reg]));
                }
                o.x = f32_bf16_rne(vals[0]); o.y = f32_bf16_rne(vals[1]);
                o.z = f32_bf16_rne(vals[2]); o.w = f32_bf16_rne(vals[3]);
                int dl = wn + nf * 16 + r;
                int tt = wm + mf * 16 + qd * 4;
                *(ushort4*)&Tr[dl * 72 + tt] = o;
            }
        }
        __syncthreads();
        u16* dst;
        if (round == 0)      dst = ekT   + ((size_t)(b * 512 + col0 + dl_r)) * 2048;
        else if (round == 1) dst = ekT   + ((size_t)(b * 512 + 256 + col0 + dl_r)) * 2048;
        else                 dst = sigqT + ((size_t)(b * 256 + col0 + dl_r)) * 2048;
        dst += t0g + tseg;
        const u16* srcp = &Tr[dl_r * 72 + tseg];
        uint4 q0 = *(const uint4*)&srcp[0];
        uint4 q1 = *(const uint4*)&srcp[8];
        *(uint4*)&dst[0] = q0;
        *(uint4*)&dst[8] = q1;
        if (round < 2) {
            const u16* h0 = (const u16*)&q0;
            const u16* h1 = (const u16*)&q1;
            float s = 0.f;
            #pragma unroll
            for (int i = 0; i < 8; ++i) s += bf16_f32(h0[i]);
            #pragma unroll
            for (int i = 0; i < 8; ++i) s += bf16_f32(h1[i]);
            s += __shfl_down(s, 1, 64);   // 4 threads per row -> tree reduce
            s += __shfl_down(s, 2, 64);
            if ((tid & 3) == 0)
                Skp[((size_t)(b * 512 + round * 256 + col0 + dl_r)) * 32 + tblk] = s;
        }
    }
}

// ---------------------------------------------------------------------------
// K2: reduce K1's partials (1MB) -> Sk (n<256), Sv (n>=256).  Replaces the
// old 33.5MB ekT re-read.
// ---------------------------------------------------------------------------
__global__ __launch_bounds__(256) void aft_sums2(
    const float* __restrict__ Skp, float* __restrict__ Sk, float* __restrict__ Sv)
{
    const int row = blockIdx.x * 256 + threadIdx.x;   // 0..8191
    const float* p = Skp + (size_t)row * 32;
    float s = 0.f;
    #pragma unroll
    for (int c = 0; c < 8; ++c) {
        float4 v = *(const float4*)&p[c * 4];
        s += v.x; s += v.y; s += v.z; s += v.w;
    }
    const int b = row >> 9, n = row & 511;
    if (n < 256) Sk[b * 256 + n] = s;
    else         Sv[b * 256 + n - 256] = s;
}

// ---------------------------------------------------------------------------
// K3: banded num/den via bf16 MFMA.  128-t tile (512 thr, 8 waves 2tx4d) --
// band redundancy 5x->3x.  Wave tile 64t x 32d (acc 64 regs).  B (ek/ekv)
// via gload_lds (R5 pattern); A (EWb) via reg+ds_write.
// R8 BUG FIXED: A source col must be UNswizzled (gchk*8) with the swizzled
// LDS dest -- R8 read source at the swizzled col too, so the two swizzles
// canceled (linear LDS) while the fragment read still applied the XOR ->
// misaligned k-slots for 3/4 of rows (absmax 6e-3).  Rule #21.
// ---------------------------------------------------------------------------
__global__ __launch_bounds__(512, 4) void aft_band_mfma(
    const u16* __restrict__ EWb, const u16* __restrict__ ekT,
    const u16* __restrict__ sigqT,
    const float* __restrict__ Sk, const float* __restrict__ Sv,
    u16* __restrict__ yTD)
{
    // main: Aw[128][32] @0 (4096 u16) + Bkv[256][32] @4096 (8192 u16)
    // epilogue: Ly[128][136] = 17408 u16 (34KB) reuses the whole span
    __shared__ alignas(16) u16 sm[17408];
    u16* Aw  = sm;            // [128][32] swizzled
    u16* Bkv = sm + 4096;     // [256][32]: rows 0..127 ek, 128..255 ekv

    const int tid  = threadIdx.x;        // 0..511
    const int t0   = blockIdx.x * 128;
    const int b    = blockIdx.y >> 1;
    const int dh   = (blockIdx.y & 1) * 128;
    const int lane = tid & 63;
    const int wid  = tid >> 6;           // 0..7
    const int th   = wid >> 2;           // t-half (0/1)
    const int wn   = (wid & 3) * 32;     // d-quarter
    const int qd   = lane >> 4;
    const int r    = lane & 15;

    f32x4 accn[4][2], accd[4][2];        // 64 VGPRs
    #pragma unroll
    for (int i = 0; i < 4; ++i)
        #pragma unroll
        for (int j = 0; j < 2; ++j) {
            accn[i][j] = (f32x4){0.f, 0.f, 0.f, 0.f};
            accd[i][j] = (f32x4){0.f, 0.f, 0.f, 0.f};
        }

    // staging coords: 512 threads cover {A: 128 rows, B: 2x128 rows} x 32 cols
    const int crow  = tid >> 2;                 // 0..127
    const int gchk  = tid & 3;
    const int cswz  = (crow >> 1) & 3;
    const int ccols = (gchk ^ cswz) * 8;        // pre-swizzled SOURCE col (B)
    const int aslot = crow * 32 + (gchk ^ cswz) * 8;  // swizzled LDS slot (A)
    const int wbase = wid * 512;                // gload dest: wave chunk (u16)
    const int sq8   = (qd ^ ((r >> 1) & 3)) * 8;

    // EWb window mapping for this thread's row: j = sc - t0 + jbase
    const int jbase = 128 - 64 * (crow >> 6);

    for (int c = 0; c < 12; ++c) {
        const int sc = t0 - 128 + c * 32;
        if (sc < 0 || sc >= T_) continue;   // uniform per block
        __syncthreads();                    // prior compute's ds_reads done
        // stage B: ek rows + ekv rows, 128 each, via gload (swizzled source)
        gload_lds16(&ekT[((size_t)(b * 512) + dh + crow) * 2048 + sc + ccols],
                    &Bkv[wbase]);
        gload_lds16(&ekT[((size_t)(b * 512) + 256 + dh + crow) * 2048 + sc + ccols],
                    &Bkv[4096 + wbase]);
        // stage A: EWb window chunk or zero -> swizzled ds_write
        // (source col UNswizzled gchk*8; dest slot swizzled -- the fix)
        {
            const int j0 = sc - t0 + jbase;   // mult of 32; window = [0,320)
            uint4 v = (uint4){0u, 0u, 0u, 0u};
            if (j0 >= 0 && j0 < 320)
                v = *(const uint4*)&EWb[(size_t)(t0 + crow) * 320 + j0 + gchk * 8];
            *(uint4*)&Aw[aslot] = v;
        }
        __syncthreads();                    // vmcnt(0) + lgkm drain

        bf16x8 af[4];
        #pragma unroll
        for (int mf = 0; mf < 4; ++mf)
            af[mf] = *(const bf16x8*)&Aw[(th * 64 + mf * 16 + r) * 32 + sq8];
        #pragma unroll
        for (int nf = 0; nf < 2; ++nf) {
            bf16x8 be = *(const bf16x8*)&Bkv[(wn + nf * 16 + r) * 32 + sq8];
            bf16x8 bv = *(const bf16x8*)&Bkv[(128 + wn + nf * 16 + r) * 32 + sq8];
            #pragma unroll
            for (int mf = 0; mf < 4; ++mf) {
                accd[mf][nf] = __builtin_amdgcn_mfma_f32_16x16x32_bf16(af[mf], be, accd[mf][nf], 0, 0, 0);
                accn[mf][nf] = __builtin_amdgcn_mfma_f32_16x16x32_bf16(af[mf], bv, accn[mf][nf], 0, 0, 0);
            }
        }
    }

    // epilogue: y into LDS [t_local][136] then coalesced store to y[b][t][d]
    __syncthreads();
    u16* Ly = sm;    // [128][136]
    #pragma unroll
    for (int nf = 0; nf < 2; ++nf) {
        const int dl = wn + nf * 16 + r;
        const int d  = dh + dl;
        const float skq = Sk[(b << 8) + d];
        const float svq = Sv[(b << 8) + d];
        #pragma unroll
        for (int mf = 0; mf < 4; ++mf) {
            const int ttl = th * 64 + mf * 16 + qd * 4;   // 0..127 local t
            size_t off = ((size_t)(b << 8) + d) * 2048 + t0 + ttl;
            ushort4 sg = *(const ushort4*)&sigqT[off];
            float s4[4] = {bf16_f32(sg.x), bf16_f32(sg.y), bf16_f32(sg.z), bf16_f32(sg.w)};
            #pragma unroll
            for (int reg = 0; reg < 4; ++reg) {
                float y = s4[reg] * (svq + accn[mf][nf][reg]) / (skq + accd[mf][nf][reg]);
                Ly[(ttl + reg) * 136 + dl] = f32_bf16_rne(y);
            }
        }
    }
    __syncthreads();
    {
        const int tl  = tid >> 2;          // 0..127
        const int ds4 = (tid & 3) * 32;    // 0..96
        u16* dst = yTD + ((size_t)b * 2048 + t0 + tl) * 256 + dh + ds4;
        #pragma unroll
        for (int i = 0; i < 4; ++i)
            *(uint4*)&dst[i * 8] = *(const uint4*)&Ly[tl * 136 + ds4 + i * 8];
    }
}

// ---------------------------------------------------------------------------
// K4: out = y @ Wo, single-bf16 both sides.  64 rows x 128 cols per block,
// grid (512, 2).  R7 version: gload_lds staging, both-sides XOR swizzle.
// ---------------------------------------------------------------------------
__global__ __launch_bounds__(256) void aft_out_mfma(
    const u16* __restrict__ yTD, const u16* __restrict__ Woth,
    float* __restrict__ out)
{
    __shared__ alignas(16) u16 sm[6144];
    u16* As = sm;           // [64][32]
    u16* Bh = sm + 2048;    // [128][32]

    const int tid  = threadIdx.x;
    const int row0 = blockIdx.x * 64;
    const int col0 = blockIdx.y * 128;
    const int lane = tid & 63;
    const int wid  = tid >> 6;
    const int wn   = wid * 32;
    const int qd   = lane >> 4;
    const int r    = lane & 15;

    f32x4 acc[4][2];
    #pragma unroll
    for (int i = 0; i < 4; ++i)
        #pragma unroll
        for (int j = 0; j < 2; ++j)
            acc[i][j] = (f32x4){0.f, 0.f, 0.f, 0.f};

    const int crow  = tid >> 2;                 // 0..63
    const int gchk  = tid & 3;
    const int cswz  = (crow >> 1) & 3;
    const int ccols = (gchk ^ cswz) * 8;        // pre-swizzled SOURCE col
    const int wbase = wid * 512;
    const int sq8   = (qd ^ ((r >> 1) & 3)) * 8;

    for (int k0 = 0; k0 < D_; k0 += 32) {
        if (k0) __syncthreads();
        gload_lds16(&yTD[(size_t)(row0 + crow) * 256 + k0 + ccols],
                    &As[wbase]);
        gload_lds16(&Woth[(size_t)(col0 + crow) * 256 + k0 + ccols],
                    &Bh[wbase]);
        gload_lds16(&Woth[(size_t)(col0 + 64 + crow) * 256 + k0 + ccols],
                    &Bh[2048 + wbase]);
        __syncthreads();

        bf16x8 af[4];
        #pragma unroll
        for (int mf = 0; mf < 4; ++mf)
            af[mf] = *(const bf16x8*)&As[(mf * 16 + r) * 32 + sq8];
        #pragma unroll
        for (int nf = 0; nf < 2; ++nf) {
            bf16x8 bh = *(const bf16x8*)&Bh[(wn + nf * 16 + r) * 32 + sq8];
            #pragma unroll
            for (int mf = 0; mf < 4; ++mf)
                acc[mf][nf] = __builtin_amdgcn_mfma_f32_16x16x32_bf16(af[mf], bh, acc[mf][nf], 0, 0, 0);
        }
    }

    #pragma unroll
    for (int mf = 0; mf < 4; ++mf)
        #pragma unroll
        for (int nf = 0; nf < 2; ++nf)
            #pragma unroll
            for (int reg = 0; reg < 4; ++reg) {
                int mrow = row0 + mf * 16 + qd * 4 + reg;
                int ncol = col0 + wn + nf * 16 + r;
                out[(size_t)mrow * D_ + ncol] = acc[mf][nf][reg];
            }
}

extern "C" void kernel_launch(void* const* d_in, const int* in_sizes, int n_in,
                              void* d_out, int out_size, void* d_ws, size_t ws_size,
                              hipStream_t stream)
{
    const float* x  = (const float*)d_in[0];
    const float* Wq = (const float*)d_in[1];
    const float* Wk = (const float*)d_in[2];
    const float* Wv = (const float*)d_in[3];
    const float* Wo = (const float*)d_in[4];
    const float* wb = (const float*)d_in[5];
    // window (d_in[6]) is the constant 128, baked in as W_.

    u16* Wth   = (u16*)d_ws;                 // 4*65536 = 262144
    u16* Wkl   = Wth + 262144;               // 65536
    u16* EWb   = Wkl + 65536;                // 655360
    u16* ekT   = EWb + 655360;               // 16777216
    u16* sigqT = ekT + 16777216;             // 8388608
    u16* yTD   = sigqT + 8388608;            // 8388608
    float* Sk  = (float*)(yTD + 8388608);    // 4096
    float* Sv  = Sk + 4096;                  // 4096
    float* Skp = Sv + 4096;                  // 8192*32 = 262144 (1MB)

    aft_split_wT<<<dim3(4, 16), 256, 0, stream>>>(Wq, Wk, Wv, Wo, Wth, Wkl);
    aft_ewb<<<dim3(T_), 320, 0, stream>>>(wb, EWb);
    aft_qkv_mfma<<<dim3(M_ / 64, 4), 256, 0, stream>>>(x, Wth, Wkl, ekT, sigqT, Skp);
    aft_sums2<<<dim3(32), 256, 0, stream>>>(Skp, Sk, Sv);
    aft_band_mfma<<<dim3(T_ / 128, B_ * 2), 512, 0, stream>>>(EWb, ekT, sigqT, Sk, Sv, yTD);
    aft_out_mfma<<<dim3(M_ / 64, 2), 256, 0, stream>>>(yTD, Wth + 3 * 65536, (float*)d_out);
}